// Round 1
// baseline (1881.757 us; speedup 1.0000x reference)
//
#include <hip/hip_runtime.h>
#include <hip/hip_bf16.h>

#define NODES_C 64
#define HEADS 4
#define HEAD_D 16

// ---------------------------------------------------------------------------
// CSR build
// ---------------------------------------------------------------------------
__global__ void count_k(const int* __restrict__ dst, int E, int* __restrict__ deg) {
    int e = blockIdx.x * blockDim.x + threadIdx.x;
    if (e < E) atomicAdd(&deg[dst[e]], 1);
}

__global__ __launch_bounds__(1024) void scan_chunk(const int* __restrict__ deg,
                                                   int* __restrict__ excl,
                                                   int* __restrict__ chunkSums, int N) {
    __shared__ int buf[1024];
    int i = blockIdx.x * 1024 + threadIdx.x;
    int v = (i < N) ? deg[i] : 0;
    buf[threadIdx.x] = v;
    __syncthreads();
    for (int off = 1; off < 1024; off <<= 1) {
        int t = (threadIdx.x >= off) ? buf[threadIdx.x - off] : 0;
        __syncthreads();
        buf[threadIdx.x] += t;
        __syncthreads();
    }
    if (i < N) excl[i] = buf[threadIdx.x] - v;   // exclusive within chunk
    if (threadIdx.x == 1023) chunkSums[blockIdx.x] = buf[1023];
}

__global__ __launch_bounds__(128) void scan_sums(int* __restrict__ chunkSums, int nChunks) {
    __shared__ int buf[128];
    int v = (threadIdx.x < nChunks) ? chunkSums[threadIdx.x] : 0;
    buf[threadIdx.x] = v;
    __syncthreads();
    for (int off = 1; off < 128; off <<= 1) {
        int t = (threadIdx.x >= off) ? buf[threadIdx.x - off] : 0;
        __syncthreads();
        buf[threadIdx.x] += t;
        __syncthreads();
    }
    if (threadIdx.x < nChunks) chunkSums[threadIdx.x] = buf[threadIdx.x] - v;  // exclusive
}

__global__ void scan_add(int* __restrict__ excl, const int* __restrict__ chunkSums,
                         int N, int E) {
    int i = blockIdx.x * blockDim.x + threadIdx.x;
    if (i < N) excl[i] += chunkSums[i >> 10];
    if (i == 0) excl[N] = E;
}

__global__ void fill_k(const int* __restrict__ dst, int E,
                       const int* __restrict__ row_start, int* __restrict__ cursor,
                       int* __restrict__ csr) {
    int e = blockIdx.x * blockDim.x + threadIdx.x;
    if (e < E) {
        int d = dst[e];
        int pos = atomicAdd(&cursor[d], 1);
        csr[row_start[d] + pos] = e;
    }
}

// ---------------------------------------------------------------------------
// Fused node projections: Q = h@Wq+bq, K = h@Wk+bk, V = h@Wv+bv, S = h@Ws+bs
// 256 threads: thread (m = tid>>6) selects matrix, (c = tid&63) output column.
// W column lives in 64 registers; h rows staged in LDS, broadcast-read.
// ---------------------------------------------------------------------------
#define GB 16
__global__ __launch_bounds__(256) void gemm_qkvs(
    const float* __restrict__ Hin,
    const float* __restrict__ Wq, const float* __restrict__ bq,
    const float* __restrict__ Wk, const float* __restrict__ bk,
    const float* __restrict__ Wv, const float* __restrict__ bv,
    const float* __restrict__ Ws, const float* __restrict__ bs,
    float* __restrict__ Q, float* __restrict__ K, float* __restrict__ V,
    float* __restrict__ Ssk, int N)
{
    int m = threadIdx.x >> 6;
    int c = threadIdx.x & 63;
    const float* W = (m == 0) ? Wq : (m == 1) ? Wk : (m == 2) ? Wv : Ws;
    const float* b = (m == 0) ? bq : (m == 1) ? bk : (m == 2) ? bv : bs;
    float* Out     = (m == 0) ? Q  : (m == 1) ? K  : (m == 2) ? V  : Ssk;

    float wcol[64];
#pragma unroll
    for (int t = 0; t < 64; ++t) wcol[t] = W[t * 64 + c];
    float bias = b[c];

    __shared__ __align__(16) float hrow[GB][64];

    for (int base = blockIdx.x * GB; base < N; base += gridDim.x * GB) {
        int nn = min(GB, N - base);
        __syncthreads();
        for (int idx = threadIdx.x; idx < nn * 64; idx += 256)
            hrow[idx >> 6][idx & 63] = Hin[base * 64 + idx];
        __syncthreads();
        for (int r = 0; r < nn; ++r) {
            const float4* h4 = (const float4*)hrow[r];
            float acc = bias;
#pragma unroll
            for (int t4 = 0; t4 < 16; ++t4) {
                float4 hv = h4[t4];
                acc += hv.x * wcol[4 * t4 + 0];
                acc += hv.y * wcol[4 * t4 + 1];
                acc += hv.z * wcol[4 * t4 + 2];
                acc += hv.w * wcol[4 * t4 + 3];
            }
            Out[(base + r) * 64 + c] = acc;
        }
    }
}

// ---------------------------------------------------------------------------
// Edge-softmax attention, gather style: one wave per destination node.
// lane = output channel c (0..63); head = c>>4; d = c&15.
// Online softmax over CSR in-edges; 2-wide edge unroll for MLP (memory ILP).
// ---------------------------------------------------------------------------
__global__ __launch_bounds__(256) void attn_k(
    const float* __restrict__ Q, const float* __restrict__ K,
    const float* __restrict__ V, const float* __restrict__ Ssk,
    const int* __restrict__ row_start, const int* __restrict__ csr,
    const int* __restrict__ srcA, const float* __restrict__ edge_attr,
    const float* __restrict__ We, const float* __restrict__ be,
    float* __restrict__ Hout, int N, int doRelu)
{
    int lane = threadIdx.x & 63;
    // We column (16 values) + bias in registers
    float wcol[16];
#pragma unroll
    for (int t = 0; t < 16; ++t) wcol[t] = We[t * 64 + lane];
    float beL = be[lane];

    int gwave  = (blockIdx.x * blockDim.x + threadIdx.x) >> 6;
    int nwaves = (gridDim.x * blockDim.x) >> 6;

    for (int i = gwave; i < N; i += nwaves) {
        float q = Q[(size_t)i * 64 + lane];
        int beg = row_start[i], end = row_start[i + 1];
        float m = -INFINITY, s = 0.f, acc = 0.f;

        int p = beg;
        // 2-wide main loop: two independent gather chains in flight
        for (; p + 1 < end; p += 2) {
            int eA = csr[p], eB = csr[p + 1];
            int jA = srcA[eA], jB = srcA[eB];
            const float4* aA = (const float4*)(edge_attr + (size_t)eA * 16);
            const float4* aB = (const float4*)(edge_attr + (size_t)eB * 16);
            float4 a0A = aA[0], a1A = aA[1], a2A = aA[2], a3A = aA[3];
            float4 a0B = aB[0], a1B = aB[1], a2B = aB[2], a3B = aB[3];
            float kA = K[(size_t)jA * 64 + lane];
            float vA = V[(size_t)jA * 64 + lane];
            float kB = K[(size_t)jB * 64 + lane];
            float vB = V[(size_t)jB * 64 + lane];

            float eaA = beL;
            eaA += a0A.x * wcol[0]  + a0A.y * wcol[1]  + a0A.z * wcol[2]  + a0A.w * wcol[3];
            eaA += a1A.x * wcol[4]  + a1A.y * wcol[5]  + a1A.z * wcol[6]  + a1A.w * wcol[7];
            eaA += a2A.x * wcol[8]  + a2A.y * wcol[9]  + a2A.z * wcol[10] + a2A.w * wcol[11];
            eaA += a3A.x * wcol[12] + a3A.y * wcol[13] + a3A.z * wcol[14] + a3A.w * wcol[15];
            float eaB = beL;
            eaB += a0B.x * wcol[0]  + a0B.y * wcol[1]  + a0B.z * wcol[2]  + a0B.w * wcol[3];
            eaB += a1B.x * wcol[4]  + a1B.y * wcol[5]  + a1B.z * wcol[6]  + a1B.w * wcol[7];
            eaB += a2B.x * wcol[8]  + a2B.y * wcol[9]  + a2B.z * wcol[10] + a2B.w * wcol[11];
            eaB += a3B.x * wcol[12] + a3B.y * wcol[13] + a3B.z * wcol[14] + a3B.w * wcol[15];

            kA += eaA; vA += eaA;
            kB += eaB; vB += eaB;

            float pA = q * kA, pB = q * kB;
#pragma unroll
            for (int off = 8; off >= 1; off >>= 1) {
                pA += __shfl_xor(pA, off, 16);
                pB += __shfl_xor(pB, off, 16);
            }
            float lA = pA * 0.25f, lB = pB * 0.25f;

            float nm = fmaxf(m, lA);
            float sc = __expf(m - nm);
            float w  = __expf(lA - nm);
            s = s * sc + w;  acc = acc * sc + w * vA;  m = nm;

            nm = fmaxf(m, lB);
            sc = __expf(m - nm);
            w  = __expf(lB - nm);
            s = s * sc + w;  acc = acc * sc + w * vB;  m = nm;
        }
        // tail
        for (; p < end; ++p) {
            int e = csr[p];
            int j = srcA[e];
            const float4* ap = (const float4*)(edge_attr + (size_t)e * 16);
            float4 a0 = ap[0], a1 = ap[1], a2 = ap[2], a3 = ap[3];
            float kv = K[(size_t)j * 64 + lane];
            float vv = V[(size_t)j * 64 + lane];
            float ea = beL;
            ea += a0.x * wcol[0]  + a0.y * wcol[1]  + a0.z * wcol[2]  + a0.w * wcol[3];
            ea += a1.x * wcol[4]  + a1.y * wcol[5]  + a1.z * wcol[6]  + a1.w * wcol[7];
            ea += a2.x * wcol[8]  + a2.y * wcol[9]  + a2.z * wcol[10] + a2.w * wcol[11];
            ea += a3.x * wcol[12] + a3.y * wcol[13] + a3.z * wcol[14] + a3.w * wcol[15];
            kv += ea; vv += ea;
            float part = q * kv;
#pragma unroll
            for (int off = 8; off >= 1; off >>= 1) part += __shfl_xor(part, off, 16);
            float logit = part * 0.25f;
            float nm = fmaxf(m, logit);
            float sc = __expf(m - nm);
            float w  = __expf(logit - nm);
            s = s * sc + w;  acc = acc * sc + w * vv;  m = nm;
        }

        float agg = (s > 0.f) ? acc / s : 0.f;
        float o = agg + Ssk[(size_t)i * 64 + lane];
        if (doRelu) o = fmaxf(o, 0.f);
        Hout[(size_t)i * 64 + lane] = o;
    }
}

// ---------------------------------------------------------------------------
// Global mean pool (atomics) + tiny MLP head
// ---------------------------------------------------------------------------
__global__ void pool_k(const float* __restrict__ H, const int* __restrict__ batch,
                       float* __restrict__ pooled, float* __restrict__ cnt, int N) {
    int idx = blockIdx.x * blockDim.x + threadIdx.x;
    if (idx < N * 64) {
        int i = idx >> 6, c = idx & 63;
        int g = batch[i];
        atomicAdd(&pooled[g * 64 + c], H[idx]);
        if (c == 0) atomicAdd(&cnt[g], 1.0f);
    }
}

__global__ __launch_bounds__(64) void mlp_k(
    const float* __restrict__ pooled, const float* __restrict__ cnt,
    const float* __restrict__ lin1_w, const float* __restrict__ lin1_b,
    const float* __restrict__ lin2_w, const float* __restrict__ lin2_b,
    float* __restrict__ out)
{
    int g = blockIdx.x;
    int c = threadIdx.x;
    float inv = 1.0f / fmaxf(cnt[g], 1.0f);
    float acc = lin1_b[c];
#pragma unroll
    for (int t = 0; t < 64; ++t) acc += pooled[g * 64 + t] * inv * lin1_w[t * 64 + c];
    float r = fmaxf(acc, 0.f) * lin2_w[c];
#pragma unroll
    for (int off = 32; off >= 1; off >>= 1) r += __shfl_xor(r, off, 64);
    if (c == 0) out[g] = r + lin2_b[0];
}

// ---------------------------------------------------------------------------
extern "C" void kernel_launch(void* const* d_in, const int* in_sizes, int n_in,
                              void* d_out, int out_size, void* d_ws, size_t ws_size,
                              hipStream_t stream) {
    const float* x        = (const float*)d_in[0];
    const int*   eidx     = (const int*)  d_in[1];
    const float* eattr    = (const float*)d_in[2];
    const int*   batch    = (const int*)  d_in[3];
    const float* Wq       = (const float*)d_in[4];
    const float* bq       = (const float*)d_in[5];
    const float* Wk       = (const float*)d_in[6];
    const float* bk       = (const float*)d_in[7];
    const float* Wv       = (const float*)d_in[8];
    const float* bv       = (const float*)d_in[9];
    const float* We       = (const float*)d_in[10];
    const float* be       = (const float*)d_in[11];
    const float* Wskip    = (const float*)d_in[12];
    const float* bskip    = (const float*)d_in[13];
    const float* lin1_w   = (const float*)d_in[14];
    const float* lin1_b   = (const float*)d_in[15];
    const float* lin2_w   = (const float*)d_in[16];
    const float* lin2_b   = (const float*)d_in[17];

    int N = in_sizes[0] / 64;
    int E = in_sizes[1] / 2;
    const int* src = eidx;
    const int* dst = eidx + E;

    // workspace layout
    char* w = (char*)d_ws;
    auto alloc = [&](size_t bytes) {
        char* p = w;
        w += (bytes + 255) & ~(size_t)255;
        return p;
    };
    float* Q   = (float*)alloc((size_t)N * 64 * 4);
    float* K   = (float*)alloc((size_t)N * 64 * 4);
    float* V   = (float*)alloc((size_t)N * 64 * 4);
    float* S   = (float*)alloc((size_t)N * 64 * 4);
    float* H   = (float*)alloc((size_t)N * 64 * 4);
    int* deg       = (int*)alloc((size_t)N * 4);
    int* row_start = (int*)alloc((size_t)(N + 1) * 4);
    int* cursor    = (int*)alloc((size_t)N * 4);
    int* csr       = (int*)alloc((size_t)E * 4);
    int* chunkSums = (int*)alloc(128 * 4);
    float* pooled  = (float*)alloc(128 * 64 * 4);
    float* cnt     = (float*)alloc(128 * 4);

    hipMemsetAsync(deg, 0, (size_t)N * 4, stream);
    hipMemsetAsync(cursor, 0, (size_t)N * 4, stream);
    hipMemsetAsync(pooled, 0, 128 * 64 * 4, stream);
    hipMemsetAsync(cnt, 0, 128 * 4, stream);

    // CSR build
    count_k<<<(E + 255) / 256, 256, 0, stream>>>(dst, E, deg);
    int nChunks = (N + 1023) / 1024;
    scan_chunk<<<nChunks, 1024, 0, stream>>>(deg, row_start, chunkSums, N);
    scan_sums<<<1, 128, 0, stream>>>(chunkSums, nChunks);
    scan_add<<<(N + 255) / 256, 256, 0, stream>>>(row_start, chunkSums, N, E);
    fill_k<<<(E + 255) / 256, 256, 0, stream>>>(dst, E, row_start, cursor, csr);

    // 3 transformer layers
    const float* Hin = x;
    for (int l = 0; l < 3; ++l) {
        gemm_qkvs<<<1024, 256, 0, stream>>>(Hin,
            Wq + l * 4096, bq + l * 64, Wk + l * 4096, bk + l * 64,
            Wv + l * 4096, bv + l * 64, Wskip + l * 4096, bskip + l * 64,
            Q, K, V, S, N);
        attn_k<<<2048, 256, 0, stream>>>(Q, K, V, S, row_start, csr, src, eattr,
            We + l * 1024, be + l * 64, H, N, (l < 2) ? 1 : 0);
        Hin = H;
    }

    // pool + head
    pool_k<<<((size_t)N * 64 + 255) / 256, 256, 0, stream>>>(Hin, batch, pooled, cnt, N);
    mlp_k<<<128, 64, 0, stream>>>(pooled, cnt, lin1_w, lin1_b, lin2_w, lin2_b,
                                  (float*)d_out);
}

// Round 3
// 1385.627 us; speedup vs baseline: 1.3581x; 1.3581x over previous
//
#include <hip/hip_runtime.h>
#include <hip/hip_bf16.h>

#define NODES_C 64
#define HEADS 4
#define HEAD_D 16

// ---------------------------------------------------------------------------
// CSR build
// ---------------------------------------------------------------------------
__global__ void count_k(const int* __restrict__ dst, int E, int* __restrict__ deg) {
    int e = blockIdx.x * blockDim.x + threadIdx.x;
    if (e < E) atomicAdd(&deg[dst[e]], 1);
}

__global__ __launch_bounds__(1024) void scan_chunk(const int* __restrict__ deg,
                                                   int* __restrict__ excl,
                                                   int* __restrict__ chunkSums, int N) {
    __shared__ int buf[1024];
    int i = blockIdx.x * 1024 + threadIdx.x;
    int v = (i < N) ? deg[i] : 0;
    buf[threadIdx.x] = v;
    __syncthreads();
    for (int off = 1; off < 1024; off <<= 1) {
        int t = (threadIdx.x >= off) ? buf[threadIdx.x - off] : 0;
        __syncthreads();
        buf[threadIdx.x] += t;
        __syncthreads();
    }
    if (i < N) excl[i] = buf[threadIdx.x] - v;   // exclusive within chunk
    if (threadIdx.x == 1023) chunkSums[blockIdx.x] = buf[1023];
}

__global__ __launch_bounds__(128) void scan_sums(int* __restrict__ chunkSums, int nChunks) {
    __shared__ int buf[128];
    int v = (threadIdx.x < nChunks) ? chunkSums[threadIdx.x] : 0;
    buf[threadIdx.x] = v;
    __syncthreads();
    for (int off = 1; off < 128; off <<= 1) {
        int t = (threadIdx.x >= off) ? buf[threadIdx.x - off] : 0;
        __syncthreads();
        buf[threadIdx.x] += t;
        __syncthreads();
    }
    if (threadIdx.x < nChunks) chunkSums[threadIdx.x] = buf[threadIdx.x] - v;  // exclusive
}

__global__ void scan_add(int* __restrict__ excl, const int* __restrict__ chunkSums,
                         int N, int E) {
    int i = blockIdx.x * blockDim.x + threadIdx.x;
    if (i < N) excl[i] += chunkSums[i >> 10];
    if (i == 0) excl[N] = E;
}

__global__ void fill_k(const int* __restrict__ dst, int E,
                       const int* __restrict__ row_start, int* __restrict__ cursor,
                       int* __restrict__ csr) {
    int e = blockIdx.x * blockDim.x + threadIdx.x;
    if (e < E) {
        int d = dst[e];
        int pos = atomicAdd(&cursor[d], 1);
        csr[row_start[d] + pos] = e;
    }
}

// ---------------------------------------------------------------------------
// Fused node projections: Q = h@Wq+bq, K = h@Wk+bk, V = h@Wv+bv, S = h@Ws+bs
// ---------------------------------------------------------------------------
#define GB 16
__global__ __launch_bounds__(256) void gemm_qkvs(
    const float* __restrict__ Hin,
    const float* __restrict__ Wq, const float* __restrict__ bq,
    const float* __restrict__ Wk, const float* __restrict__ bk,
    const float* __restrict__ Wv, const float* __restrict__ bv,
    const float* __restrict__ Ws, const float* __restrict__ bs,
    float* __restrict__ Q, float* __restrict__ K, float* __restrict__ V,
    float* __restrict__ Ssk, int N)
{
    int m = threadIdx.x >> 6;
    int c = threadIdx.x & 63;
    const float* W = (m == 0) ? Wq : (m == 1) ? Wk : (m == 2) ? Wv : Ws;
    const float* b = (m == 0) ? bq : (m == 1) ? bk : (m == 2) ? bv : bs;
    float* Out     = (m == 0) ? Q  : (m == 1) ? K  : (m == 2) ? V  : Ssk;

    float wcol[64];
#pragma unroll
    for (int t = 0; t < 64; ++t) wcol[t] = W[t * 64 + c];
    float bias = b[c];

    __shared__ __align__(16) float hrow[GB][64];

    for (int base = blockIdx.x * GB; base < N; base += gridDim.x * GB) {
        int nn = min(GB, N - base);
        __syncthreads();
        for (int idx = threadIdx.x; idx < nn * 64; idx += 256)
            hrow[idx >> 6][idx & 63] = Hin[base * 64 + idx];
        __syncthreads();
        for (int r = 0; r < nn; ++r) {
            const float4* h4 = (const float4*)hrow[r];
            float acc = bias;
#pragma unroll
            for (int t4 = 0; t4 < 16; ++t4) {
                float4 hv = h4[t4];
                acc += hv.x * wcol[4 * t4 + 0];
                acc += hv.y * wcol[4 * t4 + 1];
                acc += hv.z * wcol[4 * t4 + 2];
                acc += hv.w * wcol[4 * t4 + 3];
            }
            Out[(base + r) * 64 + c] = acc;
        }
    }
}

// ---------------------------------------------------------------------------
// Edge-softmax attention, gather style: one wave per destination node.
// ---------------------------------------------------------------------------
__global__ __launch_bounds__(256) void attn_k(
    const float* __restrict__ Q, const float* __restrict__ K,
    const float* __restrict__ V, const float* __restrict__ Ssk,
    const int* __restrict__ row_start, const int* __restrict__ csr,
    const int* __restrict__ srcA, const float* __restrict__ edge_attr,
    const float* __restrict__ We, const float* __restrict__ be,
    float* __restrict__ Hout, int N, int doRelu)
{
    int lane = threadIdx.x & 63;
    float wcol[16];
#pragma unroll
    for (int t = 0; t < 16; ++t) wcol[t] = We[t * 64 + lane];
    float beL = be[lane];

    int gwave  = (blockIdx.x * blockDim.x + threadIdx.x) >> 6;
    int nwaves = (gridDim.x * blockDim.x) >> 6;

    for (int i = gwave; i < N; i += nwaves) {
        float q = Q[(size_t)i * 64 + lane];
        int beg = row_start[i], end = row_start[i + 1];
        float m = -INFINITY, s = 0.f, acc = 0.f;

        int p = beg;
        for (; p + 1 < end; p += 2) {
            int eA = csr[p], eB = csr[p + 1];
            int jA = srcA[eA], jB = srcA[eB];
            const float4* aA = (const float4*)(edge_attr + (size_t)eA * 16);
            const float4* aB = (const float4*)(edge_attr + (size_t)eB * 16);
            float4 a0A = aA[0], a1A = aA[1], a2A = aA[2], a3A = aA[3];
            float4 a0B = aB[0], a1B = aB[1], a2B = aB[2], a3B = aB[3];
            float kA = K[(size_t)jA * 64 + lane];
            float vA = V[(size_t)jA * 64 + lane];
            float kB = K[(size_t)jB * 64 + lane];
            float vB = V[(size_t)jB * 64 + lane];

            float eaA = beL;
            eaA += a0A.x * wcol[0]  + a0A.y * wcol[1]  + a0A.z * wcol[2]  + a0A.w * wcol[3];
            eaA += a1A.x * wcol[4]  + a1A.y * wcol[5]  + a1A.z * wcol[6]  + a1A.w * wcol[7];
            eaA += a2A.x * wcol[8]  + a2A.y * wcol[9]  + a2A.z * wcol[10] + a2A.w * wcol[11];
            eaA += a3A.x * wcol[12] + a3A.y * wcol[13] + a3A.z * wcol[14] + a3A.w * wcol[15];
            float eaB = beL;
            eaB += a0B.x * wcol[0]  + a0B.y * wcol[1]  + a0B.z * wcol[2]  + a0B.w * wcol[3];
            eaB += a1B.x * wcol[4]  + a1B.y * wcol[5]  + a1B.z * wcol[6]  + a1B.w * wcol[7];
            eaB += a2B.x * wcol[8]  + a2B.y * wcol[9]  + a2B.z * wcol[10] + a2B.w * wcol[11];
            eaB += a3B.x * wcol[12] + a3B.y * wcol[13] + a3B.z * wcol[14] + a3B.w * wcol[15];

            kA += eaA; vA += eaA;
            kB += eaB; vB += eaB;

            float pA = q * kA, pB = q * kB;
#pragma unroll
            for (int off = 8; off >= 1; off >>= 1) {
                pA += __shfl_xor(pA, off, 16);
                pB += __shfl_xor(pB, off, 16);
            }
            float lA = pA * 0.25f, lB = pB * 0.25f;

            float nm = fmaxf(m, lA);
            float sc = __expf(m - nm);
            float w  = __expf(lA - nm);
            s = s * sc + w;  acc = acc * sc + w * vA;  m = nm;

            nm = fmaxf(m, lB);
            sc = __expf(m - nm);
            w  = __expf(lB - nm);
            s = s * sc + w;  acc = acc * sc + w * vB;  m = nm;
        }
        for (; p < end; ++p) {
            int e = csr[p];
            int j = srcA[e];
            const float4* ap = (const float4*)(edge_attr + (size_t)e * 16);
            float4 a0 = ap[0], a1 = ap[1], a2 = ap[2], a3 = ap[3];
            float kv = K[(size_t)j * 64 + lane];
            float vv = V[(size_t)j * 64 + lane];
            float ea = beL;
            ea += a0.x * wcol[0]  + a0.y * wcol[1]  + a0.z * wcol[2]  + a0.w * wcol[3];
            ea += a1.x * wcol[4]  + a1.y * wcol[5]  + a1.z * wcol[6]  + a1.w * wcol[7];
            ea += a2.x * wcol[8]  + a2.y * wcol[9]  + a2.z * wcol[10] + a2.w * wcol[11];
            ea += a3.x * wcol[12] + a3.y * wcol[13] + a3.z * wcol[14] + a3.w * wcol[15];
            kv += ea; vv += ea;
            float part = q * kv;
#pragma unroll
            for (int off = 8; off >= 1; off >>= 1) part += __shfl_xor(part, off, 16);
            float logit = part * 0.25f;
            float nm = fmaxf(m, logit);
            float sc = __expf(m - nm);
            float w  = __expf(logit - nm);
            s = s * sc + w;  acc = acc * sc + w * vv;  m = nm;
        }

        float agg = (s > 0.f) ? acc / s : 0.f;
        float o = agg + Ssk[(size_t)i * 64 + lane];
        if (doRelu) o = fmaxf(o, 0.f);
        Hout[(size_t)i * 64 + lane] = o;
    }
}

// ---------------------------------------------------------------------------
// Global mean pool — segmented reduction exploiting SORTED batch array.
// One wave (64 threads) per 128-node contiguous chunk; lane = channel.
// Accumulate in a register, flush one atomicAdd per graph boundary.
// Atomics: ~6.4M (old) -> ~150k (new).
// ---------------------------------------------------------------------------
#define POOL_CHUNK 128
__global__ __launch_bounds__(64) void pool_k(
    const float* __restrict__ H, const int* __restrict__ batch,
    float* __restrict__ pooled, float* __restrict__ cnt, int N)
{
    int lane = threadIdx.x;
    int beg = blockIdx.x * POOL_CHUNK;
    if (beg >= N) return;
    int end = min(beg + POOL_CHUNK, N);

    int curg = batch[beg];
    float acc = 0.f, c = 0.f;
    for (int i = beg; i < end; ++i) {
        int g = batch[i];           // uniform across wave (scalar load)
        if (g != curg) {            // uniform branch
            atomicAdd(&pooled[curg * 64 + lane], acc);
            if (lane == 0) atomicAdd(&cnt[curg], c);
            acc = 0.f; c = 0.f; curg = g;
        }
        acc += H[(size_t)i * 64 + lane];
        c += 1.0f;
    }
    atomicAdd(&pooled[curg * 64 + lane], acc);
    if (lane == 0) atomicAdd(&cnt[curg], c);
}

__global__ __launch_bounds__(64) void mlp_k(
    const float* __restrict__ pooled, const float* __restrict__ cnt,
    const float* __restrict__ lin1_w, const float* __restrict__ lin1_b,
    const float* __restrict__ lin2_w, const float* __restrict__ lin2_b,
    float* __restrict__ out)
{
    int g = blockIdx.x;
    int c = threadIdx.x;
    float inv = 1.0f / fmaxf(cnt[g], 1.0f);
    float acc = lin1_b[c];
#pragma unroll
    for (int t = 0; t < 64; ++t) acc += pooled[g * 64 + t] * inv * lin1_w[t * 64 + c];
    float r = fmaxf(acc, 0.f) * lin2_w[c];
#pragma unroll
    for (int off = 32; off >= 1; off >>= 1) r += __shfl_xor(r, off, 64);
    if (c == 0) out[g] = r + lin2_b[0];
}

// ---------------------------------------------------------------------------
extern "C" void kernel_launch(void* const* d_in, const int* in_sizes, int n_in,
                              void* d_out, int out_size, void* d_ws, size_t ws_size,
                              hipStream_t stream) {
    const float* x        = (const float*)d_in[0];
    const int*   eidx     = (const int*)  d_in[1];
    const float* eattr    = (const float*)d_in[2];
    const int*   batch    = (const int*)  d_in[3];
    const float* Wq       = (const float*)d_in[4];
    const float* bq       = (const float*)d_in[5];
    const float* Wk       = (const float*)d_in[6];
    const float* bk       = (const float*)d_in[7];
    const float* Wv       = (const float*)d_in[8];
    const float* bv       = (const float*)d_in[9];
    const float* We       = (const float*)d_in[10];
    const float* be       = (const float*)d_in[11];
    const float* Wskip    = (const float*)d_in[12];
    const float* bskip    = (const float*)d_in[13];
    const float* lin1_w   = (const float*)d_in[14];
    const float* lin1_b   = (const float*)d_in[15];
    const float* lin2_w   = (const float*)d_in[16];
    const float* lin2_b   = (const float*)d_in[17];

    int N = in_sizes[0] / 64;
    int E = in_sizes[1] / 2;
    const int* src = eidx;
    const int* dst = eidx + E;

    // workspace layout
    char* w = (char*)d_ws;
    auto alloc = [&](size_t bytes) {
        char* p = w;
        w += (bytes + 255) & ~(size_t)255;
        return p;
    };
    float* Q   = (float*)alloc((size_t)N * 64 * 4);
    float* K   = (float*)alloc((size_t)N * 64 * 4);
    float* V   = (float*)alloc((size_t)N * 64 * 4);
    float* S   = (float*)alloc((size_t)N * 64 * 4);
    float* H   = (float*)alloc((size_t)N * 64 * 4);
    int* deg       = (int*)alloc((size_t)N * 4);
    int* row_start = (int*)alloc((size_t)(N + 1) * 4);
    int* cursor    = (int*)alloc((size_t)N * 4);
    int* csr       = (int*)alloc((size_t)E * 4);
    int* chunkSums = (int*)alloc(128 * 4);
    float* pooled  = (float*)alloc(128 * 64 * 4);
    float* cnt     = (float*)alloc(128 * 4);

    hipMemsetAsync(deg, 0, (size_t)N * 4, stream);
    hipMemsetAsync(cursor, 0, (size_t)N * 4, stream);
    hipMemsetAsync(pooled, 0, 128 * 64 * 4, stream);
    hipMemsetAsync(cnt, 0, 128 * 4, stream);

    // CSR build
    count_k<<<(E + 255) / 256, 256, 0, stream>>>(dst, E, deg);
    int nChunks = (N + 1023) / 1024;
    scan_chunk<<<nChunks, 1024, 0, stream>>>(deg, row_start, chunkSums, N);
    scan_sums<<<1, 128, 0, stream>>>(chunkSums, nChunks);
    scan_add<<<(N + 255) / 256, 256, 0, stream>>>(row_start, chunkSums, N, E);
    fill_k<<<(E + 255) / 256, 256, 0, stream>>>(dst, E, row_start, cursor, csr);

    // 3 transformer layers
    const float* Hin = x;
    for (int l = 0; l < 3; ++l) {
        gemm_qkvs<<<1024, 256, 0, stream>>>(Hin,
            Wq + l * 4096, bq + l * 64, Wk + l * 4096, bk + l * 64,
            Wv + l * 4096, bv + l * 64, Wskip + l * 4096, bskip + l * 64,
            Q, K, V, S, N);
        attn_k<<<2048, 256, 0, stream>>>(Q, K, V, S, row_start, csr, src, eattr,
            We + l * 1024, be + l * 64, H, N, (l < 2) ? 1 : 0);
        Hin = H;
    }

    // pool + head
    int poolBlocks = (N + POOL_CHUNK - 1) / POOL_CHUNK;
    pool_k<<<poolBlocks, 64, 0, stream>>>(Hin, batch, pooled, cnt, N);
    mlp_k<<<128, 64, 0, stream>>>(pooled, cnt, lin1_w, lin1_b, lin2_w, lin2_b,
                                  (float*)d_out);
}

// Round 5
// 1291.824 us; speedup vs baseline: 1.4567x; 1.0726x over previous
//
#include <hip/hip_runtime.h>
#include <hip/hip_bf16.h>

#define NODES_C 64
#define HEADS 4
#define HEAD_D 16

// ---------------------------------------------------------------------------
// CSR build
// ---------------------------------------------------------------------------
__global__ void count_k(const int* __restrict__ dst, int E, int* __restrict__ deg) {
    int e = blockIdx.x * blockDim.x + threadIdx.x;
    if (e < E) atomicAdd(&deg[dst[e]], 1);
}

__global__ __launch_bounds__(1024) void scan_chunk(const int* __restrict__ deg,
                                                   int* __restrict__ excl,
                                                   int* __restrict__ chunkSums, int N) {
    __shared__ int buf[1024];
    int i = blockIdx.x * 1024 + threadIdx.x;
    int v = (i < N) ? deg[i] : 0;
    buf[threadIdx.x] = v;
    __syncthreads();
    for (int off = 1; off < 1024; off <<= 1) {
        int t = (threadIdx.x >= off) ? buf[threadIdx.x - off] : 0;
        __syncthreads();
        buf[threadIdx.x] += t;
        __syncthreads();
    }
    if (i < N) excl[i] = buf[threadIdx.x] - v;   // exclusive within chunk
    if (threadIdx.x == 1023) chunkSums[blockIdx.x] = buf[1023];
}

__global__ __launch_bounds__(128) void scan_sums(int* __restrict__ chunkSums, int nChunks) {
    __shared__ int buf[128];
    int v = (threadIdx.x < nChunks) ? chunkSums[threadIdx.x] : 0;
    buf[threadIdx.x] = v;
    __syncthreads();
    for (int off = 1; off < 128; off <<= 1) {
        int t = (threadIdx.x >= off) ? buf[threadIdx.x - off] : 0;
        __syncthreads();
        buf[threadIdx.x] += t;
        __syncthreads();
    }
    if (threadIdx.x < nChunks) chunkSums[threadIdx.x] = buf[threadIdx.x] - v;  // exclusive
}

__global__ void scan_add(int* __restrict__ excl, const int* __restrict__ chunkSums,
                         int N, int E) {
    int i = blockIdx.x * blockDim.x + threadIdx.x;
    if (i < N) excl[i] += chunkSums[i >> 10];
    if (i == 0) excl[N] = E;
}

__global__ void fill_k(const int* __restrict__ dst, int E,
                       const int* __restrict__ row_start, int* __restrict__ cursor,
                       int* __restrict__ csr) {
    int e = blockIdx.x * blockDim.x + threadIdx.x;
    if (e < E) {
        int d = dst[e];
        int pos = atomicAdd(&cursor[d], 1);
        csr[row_start[d] + pos] = e;
    }
}

// ---------------------------------------------------------------------------
// One-time edge-data permutation into CSR order.
// 4 threads per edge: thread q copies float4 #q of edge_attr row.
// Converts per-layer random 64B edge reads into sequential streams, and
// removes one level of indirection (csr -> src) from attn's dependent chain.
// ---------------------------------------------------------------------------
__global__ void gather_edges(const int* __restrict__ csr, const int* __restrict__ srcA,
                             const float4* __restrict__ ea4,
                             int* __restrict__ csr_src, float4* __restrict__ csr_ea,
                             int E) {
    int t = blockIdx.x * blockDim.x + threadIdx.x;
    int p = t >> 2, q = t & 3;
    if (p < E) {
        int e = csr[p];
        if (q == 0) csr_src[p] = srcA[e];
        csr_ea[(size_t)p * 4 + q] = ea4[(size_t)e * 4 + q];
    }
}

// ---------------------------------------------------------------------------
// Fused node projections: Q = h@Wq+bq, K = h@Wk+bk, V = h@Wv+bv, S = h@Ws+bs
// ---------------------------------------------------------------------------
#define GB 16
__global__ __launch_bounds__(256) void gemm_qkvs(
    const float* __restrict__ Hin,
    const float* __restrict__ Wq, const float* __restrict__ bq,
    const float* __restrict__ Wk, const float* __restrict__ bk,
    const float* __restrict__ Wv, const float* __restrict__ bv,
    const float* __restrict__ Ws, const float* __restrict__ bs,
    float* __restrict__ Q, float* __restrict__ K, float* __restrict__ V,
    float* __restrict__ Ssk, int N)
{
    int m = threadIdx.x >> 6;
    int c = threadIdx.x & 63;
    const float* W = (m == 0) ? Wq : (m == 1) ? Wk : (m == 2) ? Wv : Ws;
    const float* b = (m == 0) ? bq : (m == 1) ? bk : (m == 2) ? bv : bs;
    float* Out     = (m == 0) ? Q  : (m == 1) ? K  : (m == 2) ? V  : Ssk;

    float wcol[64];
#pragma unroll
    for (int t = 0; t < 64; ++t) wcol[t] = W[t * 64 + c];
    float bias = b[c];

    __shared__ __align__(16) float hrow[GB][64];

    for (int base = blockIdx.x * GB; base < N; base += gridDim.x * GB) {
        int nn = min(GB, N - base);
        __syncthreads();
        for (int idx = threadIdx.x; idx < nn * 64; idx += 256)
            hrow[idx >> 6][idx & 63] = Hin[base * 64 + idx];
        __syncthreads();
        for (int r = 0; r < nn; ++r) {
            const float4* h4 = (const float4*)hrow[r];
            float acc = bias;
#pragma unroll
            for (int t4 = 0; t4 < 16; ++t4) {
                float4 hv = h4[t4];
                acc += hv.x * wcol[4 * t4 + 0];
                acc += hv.y * wcol[4 * t4 + 1];
                acc += hv.z * wcol[4 * t4 + 2];
                acc += hv.w * wcol[4 * t4 + 3];
            }
            Out[(base + r) * 64 + c] = acc;
        }
    }
}

// ---------------------------------------------------------------------------
// Edge-softmax attention, CSR-permuted fast path.
// One wave per destination node; lane = channel; 16-lane group = head.
// 4-wide edge unroll: 8 K/V gathers in flight; edge_attr reads sequential.
// Batched online-softmax update: one rescale + 5 exp per 4 edges.
// ---------------------------------------------------------------------------
#define EA_DOT(A0, A1, A2, A3)                                                    \
    (A0.x * wc0.x + A0.y * wc0.y + A0.z * wc0.z + A0.w * wc0.w +                  \
     A1.x * wc1.x + A1.y * wc1.y + A1.z * wc1.z + A1.w * wc1.w +                  \
     A2.x * wc2.x + A2.y * wc2.y + A2.z * wc2.z + A2.w * wc2.w +                  \
     A3.x * wc3.x + A3.y * wc3.y + A3.z * wc3.z + A3.w * wc3.w)

__global__ __launch_bounds__(256) void attn_pre(
    const float* __restrict__ Q, const float* __restrict__ K,
    const float* __restrict__ V, const float* __restrict__ Ssk,
    const int* __restrict__ row_start, const int* __restrict__ csr_src,
    const float4* __restrict__ csr_ea,
    const float* __restrict__ We, const float* __restrict__ be,
    float* __restrict__ Hout, int N, int doRelu)
{
    int lane = threadIdx.x & 63;
    float4 wc0, wc1, wc2, wc3;
    wc0.x = We[0 * 64 + lane];  wc0.y = We[1 * 64 + lane];
    wc0.z = We[2 * 64 + lane];  wc0.w = We[3 * 64 + lane];
    wc1.x = We[4 * 64 + lane];  wc1.y = We[5 * 64 + lane];
    wc1.z = We[6 * 64 + lane];  wc1.w = We[7 * 64 + lane];
    wc2.x = We[8 * 64 + lane];  wc2.y = We[9 * 64 + lane];
    wc2.z = We[10 * 64 + lane]; wc2.w = We[11 * 64 + lane];
    wc3.x = We[12 * 64 + lane]; wc3.y = We[13 * 64 + lane];
    wc3.z = We[14 * 64 + lane]; wc3.w = We[15 * 64 + lane];
    float beL = be[lane];

    int gwave  = (blockIdx.x * blockDim.x + threadIdx.x) >> 6;
    int nwaves = (gridDim.x * blockDim.x) >> 6;

    for (int i = gwave; i < N; i += nwaves) {
        float q = Q[(size_t)i * 64 + lane];
        int beg = row_start[i], end = row_start[i + 1];
        float m = -INFINITY, s = 0.f, acc = 0.f;

        int p = beg;
        for (; p + 3 < end; p += 4) {
            // independent gathers — 8 in flight
            int j0 = csr_src[p],     j1 = csr_src[p + 1];
            int j2 = csr_src[p + 2], j3 = csr_src[p + 3];
            float k0 = K[(size_t)j0 * 64 + lane], v0 = V[(size_t)j0 * 64 + lane];
            float k1 = K[(size_t)j1 * 64 + lane], v1 = V[(size_t)j1 * 64 + lane];
            float k2 = K[(size_t)j2 * 64 + lane], v2 = V[(size_t)j2 * 64 + lane];
            float k3 = K[(size_t)j3 * 64 + lane], v3 = V[(size_t)j3 * 64 + lane];
            // sequential edge-attr stream (16 float4 = 256B contiguous)
            const float4* ap = csr_ea + (size_t)p * 4;
            float4 e00 = ap[0],  e01 = ap[1],  e02 = ap[2],  e03 = ap[3];
            float4 e10 = ap[4],  e11 = ap[5],  e12 = ap[6],  e13 = ap[7];
            float4 e20 = ap[8],  e21 = ap[9],  e22 = ap[10], e23 = ap[11];
            float4 e30 = ap[12], e31 = ap[13], e32 = ap[14], e33 = ap[15];

            float ea0 = beL + EA_DOT(e00, e01, e02, e03);
            float ea1 = beL + EA_DOT(e10, e11, e12, e13);
            float ea2 = beL + EA_DOT(e20, e21, e22, e23);
            float ea3 = beL + EA_DOT(e30, e31, e32, e33);

            k0 += ea0; v0 += ea0;
            k1 += ea1; v1 += ea1;
            k2 += ea2; v2 += ea2;
            k3 += ea3; v3 += ea3;

            float l0 = q * k0, l1 = q * k1, l2 = q * k2, l3 = q * k3;
#pragma unroll
            for (int off = 8; off >= 1; off >>= 1) {
                l0 += __shfl_xor(l0, off, 16);
                l1 += __shfl_xor(l1, off, 16);
                l2 += __shfl_xor(l2, off, 16);
                l3 += __shfl_xor(l3, off, 16);
            }
            l0 *= 0.25f; l1 *= 0.25f; l2 *= 0.25f; l3 *= 0.25f;

            // batched online-softmax update: one rescale, 5 exp per 4 edges
            float nm = fmaxf(fmaxf(fmaxf(l0, l1), fmaxf(l2, l3)), m);
            float sc = __expf(m - nm);
            float w0 = __expf(l0 - nm), w1 = __expf(l1 - nm);
            float w2 = __expf(l2 - nm), w3 = __expf(l3 - nm);
            s   = s * sc + w0 + w1 + w2 + w3;
            acc = acc * sc + w0 * v0 + w1 * v1 + w2 * v2 + w3 * v3;
            m = nm;
        }
        for (; p < end; ++p) {
            int j = csr_src[p];
            float kv = K[(size_t)j * 64 + lane];
            float vv = V[(size_t)j * 64 + lane];
            const float4* ap = csr_ea + (size_t)p * 4;
            float4 a0 = ap[0], a1 = ap[1], a2 = ap[2], a3 = ap[3];
            float ea = beL + EA_DOT(a0, a1, a2, a3);
            kv += ea; vv += ea;
            float l = q * kv;
#pragma unroll
            for (int off = 8; off >= 1; off >>= 1) l += __shfl_xor(l, off, 16);
            l *= 0.25f;
            float nm = fmaxf(m, l);
            float sc = __expf(m - nm);
            float w  = __expf(l - nm);
            s = s * sc + w;  acc = acc * sc + w * vv;  m = nm;
        }

        float agg = (s > 0.f) ? acc / s : 0.f;
        float o = agg + Ssk[(size_t)i * 64 + lane];
        if (doRelu) o = fmaxf(o, 0.f);
        Hout[(size_t)i * 64 + lane] = o;
    }
}

// ---------------------------------------------------------------------------
// Fallback attention (R3 version) — used only if ws_size can't hold csr_ea.
// ---------------------------------------------------------------------------
__global__ __launch_bounds__(256) void attn_k(
    const float* __restrict__ Q, const float* __restrict__ K,
    const float* __restrict__ V, const float* __restrict__ Ssk,
    const int* __restrict__ row_start, const int* __restrict__ csr,
    const int* __restrict__ srcA, const float* __restrict__ edge_attr,
    const float* __restrict__ We, const float* __restrict__ be,
    float* __restrict__ Hout, int N, int doRelu)
{
    int lane = threadIdx.x & 63;
    float wcol[16];
#pragma unroll
    for (int t = 0; t < 16; ++t) wcol[t] = We[t * 64 + lane];
    float beL = be[lane];

    int gwave  = (blockIdx.x * blockDim.x + threadIdx.x) >> 6;
    int nwaves = (gridDim.x * blockDim.x) >> 6;

    for (int i = gwave; i < N; i += nwaves) {
        float q = Q[(size_t)i * 64 + lane];
        int beg = row_start[i], end = row_start[i + 1];
        float m = -INFINITY, s = 0.f, acc = 0.f;
        for (int p = beg; p < end; ++p) {
            int e = csr[p];
            int j = srcA[e];
            const float4* ap = (const float4*)(edge_attr + (size_t)e * 16);
            float4 a0 = ap[0], a1 = ap[1], a2 = ap[2], a3 = ap[3];
            float kv = K[(size_t)j * 64 + lane];
            float vv = V[(size_t)j * 64 + lane];
            float ea = beL;
            ea += a0.x * wcol[0]  + a0.y * wcol[1]  + a0.z * wcol[2]  + a0.w * wcol[3];
            ea += a1.x * wcol[4]  + a1.y * wcol[5]  + a1.z * wcol[6]  + a1.w * wcol[7];
            ea += a2.x * wcol[8]  + a2.y * wcol[9]  + a2.z * wcol[10] + a2.w * wcol[11];
            ea += a3.x * wcol[12] + a3.y * wcol[13] + a3.z * wcol[14] + a3.w * wcol[15];
            kv += ea; vv += ea;
            float part = q * kv;
#pragma unroll
            for (int off = 8; off >= 1; off >>= 1) part += __shfl_xor(part, off, 16);
            float logit = part * 0.25f;
            float nm = fmaxf(m, logit);
            float sc = __expf(m - nm);
            float w  = __expf(logit - nm);
            s = s * sc + w;  acc = acc * sc + w * vv;  m = nm;
        }
        float agg = (s > 0.f) ? acc / s : 0.f;
        float o = agg + Ssk[(size_t)i * 64 + lane];
        if (doRelu) o = fmaxf(o, 0.f);
        Hout[(size_t)i * 64 + lane] = o;
    }
}

// ---------------------------------------------------------------------------
// Global mean pool — segmented reduction exploiting SORTED batch array.
// ---------------------------------------------------------------------------
#define POOL_CHUNK 128
__global__ __launch_bounds__(64) void pool_k(
    const float* __restrict__ H, const int* __restrict__ batch,
    float* __restrict__ pooled, float* __restrict__ cnt, int N)
{
    int lane = threadIdx.x;
    int beg = blockIdx.x * POOL_CHUNK;
    if (beg >= N) return;
    int end = min(beg + POOL_CHUNK, N);

    int curg = batch[beg];
    float acc = 0.f, c = 0.f;
    for (int i = beg; i < end; ++i) {
        int g = batch[i];           // uniform across wave
        if (g != curg) {            // uniform branch
            atomicAdd(&pooled[curg * 64 + lane], acc);
            if (lane == 0) atomicAdd(&cnt[curg], c);
            acc = 0.f; c = 0.f; curg = g;
        }
        acc += H[(size_t)i * 64 + lane];
        c += 1.0f;
    }
    atomicAdd(&pooled[curg * 64 + lane], acc);
    if (lane == 0) atomicAdd(&cnt[curg], c);
}

__global__ __launch_bounds__(64) void mlp_k(
    const float* __restrict__ pooled, const float* __restrict__ cnt,
    const float* __restrict__ lin1_w, const float* __restrict__ lin1_b,
    const float* __restrict__ lin2_w, const float* __restrict__ lin2_b,
    float* __restrict__ out)
{
    int g = blockIdx.x;
    int c = threadIdx.x;
    float inv = 1.0f / fmaxf(cnt[g], 1.0f);
    float acc = lin1_b[c];
#pragma unroll
    for (int t = 0; t < 64; ++t) acc += pooled[g * 64 + t] * inv * lin1_w[t * 64 + c];
    float r = fmaxf(acc, 0.f) * lin2_w[c];
#pragma unroll
    for (int off = 32; off >= 1; off >>= 1) r += __shfl_xor(r, off, 64);
    if (c == 0) out[g] = r + lin2_b[0];
}

// ---------------------------------------------------------------------------
extern "C" void kernel_launch(void* const* d_in, const int* in_sizes, int n_in,
                              void* d_out, int out_size, void* d_ws, size_t ws_size,
                              hipStream_t stream) {
    const float* x        = (const float*)d_in[0];
    const int*   eidx     = (const int*)  d_in[1];
    const float* eattr    = (const float*)d_in[2];
    const int*   batch    = (const int*)  d_in[3];
    const float* Wq       = (const float*)d_in[4];
    const float* bq       = (const float*)d_in[5];
    const float* Wk       = (const float*)d_in[6];
    const float* bk       = (const float*)d_in[7];
    const float* Wv       = (const float*)d_in[8];
    const float* bv       = (const float*)d_in[9];
    const float* We       = (const float*)d_in[10];
    const float* be       = (const float*)d_in[11];
    const float* Wskip    = (const float*)d_in[12];
    const float* bskip    = (const float*)d_in[13];
    const float* lin1_w   = (const float*)d_in[14];
    const float* lin1_b   = (const float*)d_in[15];
    const float* lin2_w   = (const float*)d_in[16];
    const float* lin2_b   = (const float*)d_in[17];

    int N = in_sizes[0] / 64;
    int E = in_sizes[1] / 2;
    const int* src = eidx;
    const int* dst = eidx + E;

    // workspace layout
    char* w = (char*)d_ws;
    auto alloc = [&](size_t bytes) {
        char* p = w;
        w += (bytes + 255) & ~(size_t)255;
        return p;
    };
    float* Q   = (float*)alloc((size_t)N * 64 * 4);
    float* K   = (float*)alloc((size_t)N * 64 * 4);
    float* V   = (float*)alloc((size_t)N * 64 * 4);
    float* S   = (float*)alloc((size_t)N * 64 * 4);
    float* H   = (float*)alloc((size_t)N * 64 * 4);
    int* deg       = (int*)alloc((size_t)N * 4);
    int* row_start = (int*)alloc((size_t)(N + 1) * 4);
    int* cursor    = (int*)alloc((size_t)N * 4);
    int* csr       = (int*)alloc((size_t)E * 4);
    int* chunkSums = (int*)alloc(128 * 4);
    float* pooled  = (float*)alloc(128 * 64 * 4);
    float* cnt     = (float*)alloc(128 * 4);
    // fast-path extras (checked against ws_size)
    int*    csr_src = (int*)   alloc((size_t)E * 4);
    float4* csr_ea  = (float4*)alloc((size_t)E * 16 * 4);
    bool pre = ((size_t)(w - (char*)d_ws) <= ws_size);

    hipMemsetAsync(deg, 0, (size_t)N * 4, stream);
    hipMemsetAsync(cursor, 0, (size_t)N * 4, stream);
    hipMemsetAsync(pooled, 0, 128 * 64 * 4, stream);
    hipMemsetAsync(cnt, 0, 128 * 4, stream);

    // CSR build
    count_k<<<(E + 255) / 256, 256, 0, stream>>>(dst, E, deg);
    int nChunks = (N + 1023) / 1024;
    scan_chunk<<<nChunks, 1024, 0, stream>>>(deg, row_start, chunkSums, N);
    scan_sums<<<1, 128, 0, stream>>>(chunkSums, nChunks);
    scan_add<<<(N + 255) / 256, 256, 0, stream>>>(row_start, chunkSums, N, E);
    fill_k<<<(E + 255) / 256, 256, 0, stream>>>(dst, E, row_start, cursor, csr);

    // one-time edge-data permutation into CSR order
    if (pre) {
        gather_edges<<<((size_t)E * 4 + 255) / 256, 256, 0, stream>>>(
            csr, src, (const float4*)eattr, csr_src, csr_ea, E);
    }

    // 3 transformer layers
    const float* Hin = x;
    for (int l = 0; l < 3; ++l) {
        gemm_qkvs<<<1024, 256, 0, stream>>>(Hin,
            Wq + l * 4096, bq + l * 64, Wk + l * 4096, bk + l * 64,
            Wv + l * 4096, bv + l * 64, Wskip + l * 4096, bskip + l * 64,
            Q, K, V, S, N);
        if (pre) {
            attn_pre<<<2048, 256, 0, stream>>>(Q, K, V, S, row_start, csr_src, csr_ea,
                We + l * 1024, be + l * 64, H, N, (l < 2) ? 1 : 0);
        } else {
            attn_k<<<2048, 256, 0, stream>>>(Q, K, V, S, row_start, csr, src, eattr,
                We + l * 1024, be + l * 64, H, N, (l < 2) ? 1 : 0);
        }
        Hin = H;
    }

    // pool + head
    int poolBlocks = (N + POOL_CHUNK - 1) / POOL_CHUNK;
    pool_k<<<poolBlocks, 64, 0, stream>>>(Hin, batch, pooled, cnt, N);
    mlp_k<<<128, 64, 0, stream>>>(pooled, cnt, lin1_w, lin1_b, lin2_w, lin2_b,
                                  (float*)d_out);
}

// Round 6
// 1063.931 us; speedup vs baseline: 1.7687x; 1.2142x over previous
//
#include <hip/hip_runtime.h>
#include <hip/hip_bf16.h>

#define NODES_C 64
#define HEADS 4
#define HEAD_D 16

// ---------------------------------------------------------------------------
// CSR build
// ---------------------------------------------------------------------------
__global__ void count_k(const int* __restrict__ dst, int E, int* __restrict__ deg) {
    int e = blockIdx.x * blockDim.x + threadIdx.x;
    if (e < E) atomicAdd(&deg[dst[e]], 1);
}

__global__ __launch_bounds__(1024) void scan_chunk(const int* __restrict__ deg,
                                                   int* __restrict__ excl,
                                                   int* __restrict__ chunkSums, int N) {
    __shared__ int buf[1024];
    int i = blockIdx.x * 1024 + threadIdx.x;
    int v = (i < N) ? deg[i] : 0;
    buf[threadIdx.x] = v;
    __syncthreads();
    for (int off = 1; off < 1024; off <<= 1) {
        int t = (threadIdx.x >= off) ? buf[threadIdx.x - off] : 0;
        __syncthreads();
        buf[threadIdx.x] += t;
        __syncthreads();
    }
    if (i < N) excl[i] = buf[threadIdx.x] - v;   // exclusive within chunk
    if (threadIdx.x == 1023) chunkSums[blockIdx.x] = buf[1023];
}

__global__ __launch_bounds__(128) void scan_sums(int* __restrict__ chunkSums, int nChunks) {
    __shared__ int buf[128];
    int v = (threadIdx.x < nChunks) ? chunkSums[threadIdx.x] : 0;
    buf[threadIdx.x] = v;
    __syncthreads();
    for (int off = 1; off < 128; off <<= 1) {
        int t = (threadIdx.x >= off) ? buf[threadIdx.x - off] : 0;
        __syncthreads();
        buf[threadIdx.x] += t;
        __syncthreads();
    }
    if (threadIdx.x < nChunks) chunkSums[threadIdx.x] = buf[threadIdx.x] - v;  // exclusive
}

__global__ void scan_add(int* __restrict__ excl, const int* __restrict__ chunkSums,
                         int N, int E) {
    int i = blockIdx.x * blockDim.x + threadIdx.x;
    if (i < N) excl[i] += chunkSums[i >> 10];
    if (i == 0) excl[N] = E;
}

__global__ void fill_k(const int* __restrict__ dst, int E,
                       const int* __restrict__ row_start, int* __restrict__ cursor,
                       int* __restrict__ csr) {
    int e = blockIdx.x * blockDim.x + threadIdx.x;
    if (e < E) {
        int d = dst[e];
        int pos = atomicAdd(&cursor[d], 1);
        csr[row_start[d] + pos] = e;
    }
}

// ---------------------------------------------------------------------------
// One-time edge-data permutation into CSR order.
// ---------------------------------------------------------------------------
__global__ void gather_edges(const int* __restrict__ csr, const int* __restrict__ srcA,
                             const float4* __restrict__ ea4,
                             int* __restrict__ csr_src, float4* __restrict__ csr_ea,
                             int E) {
    int t = blockIdx.x * blockDim.x + threadIdx.x;
    int p = t >> 2, q = t & 3;
    if (p < E) {
        int e = csr[p];
        if (q == 0) csr_src[p] = srcA[e];
        csr_ea[(size_t)p * 4 + q] = ea4[(size_t)e * 4 + q];
    }
}

// ---------------------------------------------------------------------------
// Fused node projections. K and V are written INTERLEAVED per channel:
// KV[n*128 + 2c] = K, KV[n*128 + 2c + 1] = V  -> attn gathers one float2/edge.
// ---------------------------------------------------------------------------
#define GB 16
__global__ __launch_bounds__(256) void gemm_qkvs(
    const float* __restrict__ Hin,
    const float* __restrict__ Wq, const float* __restrict__ bq,
    const float* __restrict__ Wk, const float* __restrict__ bk,
    const float* __restrict__ Wv, const float* __restrict__ bv,
    const float* __restrict__ Ws, const float* __restrict__ bs,
    float* __restrict__ Q, float* __restrict__ KV,
    float* __restrict__ Ssk, int N)
{
    int m = threadIdx.x >> 6;
    int c = threadIdx.x & 63;
    const float* W = (m == 0) ? Wq : (m == 1) ? Wk : (m == 2) ? Wv : Ws;
    const float* b = (m == 0) ? bq : (m == 1) ? bk : (m == 2) ? bv : bs;
    float* Out     = (m == 0) ? Q  : (m == 3) ? Ssk : KV;
    size_t rowStride = (m == 1 || m == 2) ? 128 : 64;
    int cOff = (m == 1) ? 2 * c : (m == 2) ? 2 * c + 1 : c;

    float wcol[64];
#pragma unroll
    for (int t = 0; t < 64; ++t) wcol[t] = W[t * 64 + c];
    float bias = b[c];

    __shared__ __align__(16) float hrow[GB][64];

    for (int base = blockIdx.x * GB; base < N; base += gridDim.x * GB) {
        int nn = min(GB, N - base);
        __syncthreads();
        for (int idx = threadIdx.x; idx < nn * 64; idx += 256)
            hrow[idx >> 6][idx & 63] = Hin[base * 64 + idx];
        __syncthreads();
        for (int r = 0; r < nn; ++r) {
            const float4* h4 = (const float4*)hrow[r];
            float acc = bias;
#pragma unroll
            for (int t4 = 0; t4 < 16; ++t4) {
                float4 hv = h4[t4];
                acc += hv.x * wcol[4 * t4 + 0];
                acc += hv.y * wcol[4 * t4 + 1];
                acc += hv.z * wcol[4 * t4 + 2];
                acc += hv.w * wcol[4 * t4 + 3];
            }
            Out[(size_t)(base + r) * rowStride + cOff] = acc;
        }
    }
}

// ---------------------------------------------------------------------------
// Edge-softmax attention, algebraically refactored:
//   logit = ( q·k_j  +  Σ_t a_t G_{h,t}  +  q_h·be_h ) / 4
//   agg_c = (acc_c + Σ_t We[t][c] z_{h,t}) / s + be_c
// where per node: G_{h,t} = Σ_{c∈h} q_c We[t][c] (from LDS-staged We),
// and per edge, lane (h,t) keeps z += w·a_t. Per edge per lane:
// ONE float2 KV gather + ONE 4B a-broadcast + 2 FMA + 16-lane reduce.
// ---------------------------------------------------------------------------
__global__ __launch_bounds__(256) void attn_pre(
    const float* __restrict__ Q, const float2* __restrict__ KV,
    const float* __restrict__ Ssk,
    const int* __restrict__ row_start, const int* __restrict__ csr_src,
    const float* __restrict__ csr_ea,      // [E][16], CSR order
    const float* __restrict__ We, const float* __restrict__ be,
    float* __restrict__ Hout, int N, int doRelu)
{
    __shared__ float weS[16 * 68];          // padded rows: bank-spread
    for (int idx = threadIdx.x; idx < 1024; idx += 256)
        weS[(idx >> 6) * 68 + (idx & 63)] = We[idx];
    __syncthreads();

    int lane = threadIdx.x & 63;
    int tl = lane & 15;                     // edge-attr dim owned by this lane
    int hb = lane & 48;                     // head base channel
    float wcol[16];
#pragma unroll
    for (int t = 0; t < 16; ++t) wcol[t] = weS[t * 68 + lane];
    float beL = be[lane];

    int gwave  = (blockIdx.x * blockDim.x + threadIdx.x) >> 6;
    int nwaves = (gridDim.x * blockDim.x) >> 6;

    for (int i = gwave; i < N; i += nwaves) {
        float q = Q[(size_t)i * 64 + lane];

        // ---- per-node prologue ----
        // G = Σ_u We[tl][hb+u] * q[hb+u]
        const float4* qh4 = (const float4*)(Q + (size_t)i * 64 + hb);
        const float4* wr4 = (const float4*)(weS + tl * 68 + hb);
        float4 qa = qh4[0], qb4 = qh4[1], qc4 = qh4[2], qd = qh4[3];
        float4 wa = wr4[0], wb = wr4[1], wc4 = wr4[2], wd = wr4[3];
        float G = qa.x * wa.x + qa.y * wa.y + qa.z * wa.z + qa.w * wa.w
                + qb4.x * wb.x + qb4.y * wb.y + qb4.z * wb.z + qb4.w * wb.w
                + qc4.x * wc4.x + qc4.y * wc4.y + qc4.z * wc4.z + qc4.w * wc4.w
                + qd.x * wd.x + qd.y * wd.y + qd.z * wd.z + qd.w * wd.w;
        // qbase = (q_h · be_h) / 4   via 16-lane reduce
        float rb = q * beL;
#pragma unroll
        for (int off = 8; off >= 1; off >>= 1) rb += __shfl_xor(rb, off, 16);
        float qbase = rb * 0.25f;

        int beg = row_start[i], end = row_start[i + 1];
        float m = -INFINITY, s = 0.f, acc = 0.f, z = 0.f;

        int p = beg;
        for (; p + 3 < end; p += 4) {
            int j0 = csr_src[p],     j1 = csr_src[p + 1];
            int j2 = csr_src[p + 2], j3 = csr_src[p + 3];
            float2 kv0 = KV[(size_t)j0 * 64 + lane];
            float2 kv1 = KV[(size_t)j1 * 64 + lane];
            float2 kv2 = KV[(size_t)j2 * 64 + lane];
            float2 kv3 = KV[(size_t)j3 * 64 + lane];
            float a0 = csr_ea[(size_t)p * 16 + tl];
            float a1 = csr_ea[(size_t)p * 16 + 16 + tl];
            float a2 = csr_ea[(size_t)p * 16 + 32 + tl];
            float a3 = csr_ea[(size_t)p * 16 + 48 + tl];

            float l0 = q * kv0.x + a0 * G;
            float l1 = q * kv1.x + a1 * G;
            float l2 = q * kv2.x + a2 * G;
            float l3 = q * kv3.x + a3 * G;
#pragma unroll
            for (int off = 8; off >= 1; off >>= 1) {
                l0 += __shfl_xor(l0, off, 16);
                l1 += __shfl_xor(l1, off, 16);
                l2 += __shfl_xor(l2, off, 16);
                l3 += __shfl_xor(l3, off, 16);
            }
            l0 = l0 * 0.25f + qbase;
            l1 = l1 * 0.25f + qbase;
            l2 = l2 * 0.25f + qbase;
            l3 = l3 * 0.25f + qbase;

            float nm = fmaxf(fmaxf(fmaxf(l0, l1), fmaxf(l2, l3)), m);
            float sc = __expf(m - nm);
            float w0 = __expf(l0 - nm), w1 = __expf(l1 - nm);
            float w2 = __expf(l2 - nm), w3 = __expf(l3 - nm);
            s   = s * sc + w0 + w1 + w2 + w3;
            acc = acc * sc + w0 * kv0.y + w1 * kv1.y + w2 * kv2.y + w3 * kv3.y;
            z   = z * sc + w0 * a0 + w1 * a1 + w2 * a2 + w3 * a3;
            m = nm;
        }
        for (; p < end; ++p) {
            int j = csr_src[p];
            float2 kv = KV[(size_t)j * 64 + lane];
            float a = csr_ea[(size_t)p * 16 + tl];
            float l = q * kv.x + a * G;
#pragma unroll
            for (int off = 8; off >= 1; off >>= 1) l += __shfl_xor(l, off, 16);
            l = l * 0.25f + qbase;
            float nm = fmaxf(m, l);
            float sc = __expf(m - nm);
            float w  = __expf(l - nm);
            s   = s * sc + w;
            acc = acc * sc + w * kv.y;
            z   = z * sc + w * a;
            m = nm;
        }

        // ---- epilogue: fold edge-projection back in ----
        float o;
        if (s > 0.f) {
            float t = acc;
#pragma unroll
            for (int u = 0; u < 16; ++u) t += wcol[u] * __shfl(z, u, 16);
            o = t / s + beL + Ssk[(size_t)i * 64 + lane];
        } else {
            o = Ssk[(size_t)i * 64 + lane];
        }
        if (doRelu) o = fmaxf(o, 0.f);
        Hout[(size_t)i * 64 + lane] = o;
    }
}

// ---------------------------------------------------------------------------
// Fallback attention (direct algorithm) — only if ws can't hold csr_ea.
// ---------------------------------------------------------------------------
__global__ __launch_bounds__(256) void attn_k(
    const float* __restrict__ Q, const float2* __restrict__ KV,
    const float* __restrict__ Ssk,
    const int* __restrict__ row_start, const int* __restrict__ csr,
    const int* __restrict__ srcA, const float* __restrict__ edge_attr,
    const float* __restrict__ We, const float* __restrict__ be,
    float* __restrict__ Hout, int N, int doRelu)
{
    int lane = threadIdx.x & 63;
    float wcol[16];
#pragma unroll
    for (int t = 0; t < 16; ++t) wcol[t] = We[t * 64 + lane];
    float beL = be[lane];

    int gwave  = (blockIdx.x * blockDim.x + threadIdx.x) >> 6;
    int nwaves = (gridDim.x * blockDim.x) >> 6;

    for (int i = gwave; i < N; i += nwaves) {
        float q = Q[(size_t)i * 64 + lane];
        int beg = row_start[i], end = row_start[i + 1];
        float m = -INFINITY, s = 0.f, acc = 0.f;
        for (int p = beg; p < end; ++p) {
            int e = csr[p];
            int j = srcA[e];
            const float4* ap = (const float4*)(edge_attr + (size_t)e * 16);
            float4 a0 = ap[0], a1 = ap[1], a2 = ap[2], a3 = ap[3];
            float2 kvp = KV[(size_t)j * 64 + lane];
            float ea = beL;
            ea += a0.x * wcol[0]  + a0.y * wcol[1]  + a0.z * wcol[2]  + a0.w * wcol[3];
            ea += a1.x * wcol[4]  + a1.y * wcol[5]  + a1.z * wcol[6]  + a1.w * wcol[7];
            ea += a2.x * wcol[8]  + a2.y * wcol[9]  + a2.z * wcol[10] + a2.w * wcol[11];
            ea += a3.x * wcol[12] + a3.y * wcol[13] + a3.z * wcol[14] + a3.w * wcol[15];
            float kv = kvp.x + ea, vv = kvp.y + ea;
            float part = q * kv;
#pragma unroll
            for (int off = 8; off >= 1; off >>= 1) part += __shfl_xor(part, off, 16);
            float logit = part * 0.25f;
            float nm = fmaxf(m, logit);
            float sc = __expf(m - nm);
            float w  = __expf(logit - nm);
            s = s * sc + w;  acc = acc * sc + w * vv;  m = nm;
        }
        float agg = (s > 0.f) ? acc / s : 0.f;
        float o = agg + Ssk[(size_t)i * 64 + lane];
        if (doRelu) o = fmaxf(o, 0.f);
        Hout[(size_t)i * 64 + lane] = o;
    }
}

// ---------------------------------------------------------------------------
// Global mean pool — segmented reduction exploiting SORTED batch array.
// ---------------------------------------------------------------------------
#define POOL_CHUNK 128
__global__ __launch_bounds__(64) void pool_k(
    const float* __restrict__ H, const int* __restrict__ batch,
    float* __restrict__ pooled, float* __restrict__ cnt, int N)
{
    int lane = threadIdx.x;
    int beg = blockIdx.x * POOL_CHUNK;
    if (beg >= N) return;
    int end = min(beg + POOL_CHUNK, N);

    int curg = batch[beg];
    float acc = 0.f, c = 0.f;
    for (int i = beg; i < end; ++i) {
        int g = batch[i];           // uniform across wave
        if (g != curg) {            // uniform branch
            atomicAdd(&pooled[curg * 64 + lane], acc);
            if (lane == 0) atomicAdd(&cnt[curg], c);
            acc = 0.f; c = 0.f; curg = g;
        }
        acc += H[(size_t)i * 64 + lane];
        c += 1.0f;
    }
    atomicAdd(&pooled[curg * 64 + lane], acc);
    if (lane == 0) atomicAdd(&cnt[curg], c);
}

__global__ __launch_bounds__(64) void mlp_k(
    const float* __restrict__ pooled, const float* __restrict__ cnt,
    const float* __restrict__ lin1_w, const float* __restrict__ lin1_b,
    const float* __restrict__ lin2_w, const float* __restrict__ lin2_b,
    float* __restrict__ out)
{
    int g = blockIdx.x;
    int c = threadIdx.x;
    float inv = 1.0f / fmaxf(cnt[g], 1.0f);
    float acc = lin1_b[c];
#pragma unroll
    for (int t = 0; t < 64; ++t) acc += pooled[g * 64 + t] * inv * lin1_w[t * 64 + c];
    float r = fmaxf(acc, 0.f) * lin2_w[c];
#pragma unroll
    for (int off = 32; off >= 1; off >>= 1) r += __shfl_xor(r, off, 64);
    if (c == 0) out[g] = r + lin2_b[0];
}

// ---------------------------------------------------------------------------
extern "C" void kernel_launch(void* const* d_in, const int* in_sizes, int n_in,
                              void* d_out, int out_size, void* d_ws, size_t ws_size,
                              hipStream_t stream) {
    const float* x        = (const float*)d_in[0];
    const int*   eidx     = (const int*)  d_in[1];
    const float* eattr    = (const float*)d_in[2];
    const int*   batch    = (const int*)  d_in[3];
    const float* Wq       = (const float*)d_in[4];
    const float* bq       = (const float*)d_in[5];
    const float* Wk       = (const float*)d_in[6];
    const float* bk       = (const float*)d_in[7];
    const float* Wv       = (const float*)d_in[8];
    const float* bv       = (const float*)d_in[9];
    const float* We       = (const float*)d_in[10];
    const float* be       = (const float*)d_in[11];
    const float* Wskip    = (const float*)d_in[12];
    const float* bskip    = (const float*)d_in[13];
    const float* lin1_w   = (const float*)d_in[14];
    const float* lin1_b   = (const float*)d_in[15];
    const float* lin2_w   = (const float*)d_in[16];
    const float* lin2_b   = (const float*)d_in[17];

    int N = in_sizes[0] / 64;
    int E = in_sizes[1] / 2;
    const int* src = eidx;
    const int* dst = eidx + E;

    // workspace layout
    char* w = (char*)d_ws;
    auto alloc = [&](size_t bytes) {
        char* p = w;
        w += (bytes + 255) & ~(size_t)255;
        return p;
    };
    float* Q   = (float*)alloc((size_t)N * 64 * 4);
    float* KV  = (float*)alloc((size_t)N * 128 * 4);   // interleaved K,V
    float* S   = (float*)alloc((size_t)N * 64 * 4);
    float* H   = (float*)alloc((size_t)N * 64 * 4);
    int* deg       = (int*)alloc((size_t)N * 4);
    int* row_start = (int*)alloc((size_t)(N + 1) * 4);
    int* cursor    = (int*)alloc((size_t)N * 4);
    int* csr       = (int*)alloc((size_t)E * 4);
    int* chunkSums = (int*)alloc(128 * 4);
    float* pooled  = (float*)alloc(128 * 64 * 4);
    float* cnt     = (float*)alloc(128 * 4);
    // fast-path extras (checked against ws_size)
    int*    csr_src = (int*)   alloc((size_t)E * 4);
    float4* csr_ea  = (float4*)alloc((size_t)E * 16 * 4);
    bool pre = ((size_t)(w - (char*)d_ws) <= ws_size);

    hipMemsetAsync(deg, 0, (size_t)N * 4, stream);
    hipMemsetAsync(cursor, 0, (size_t)N * 4, stream);
    hipMemsetAsync(pooled, 0, 128 * 64 * 4, stream);
    hipMemsetAsync(cnt, 0, 128 * 4, stream);

    // CSR build
    count_k<<<(E + 255) / 256, 256, 0, stream>>>(dst, E, deg);
    int nChunks = (N + 1023) / 1024;
    scan_chunk<<<nChunks, 1024, 0, stream>>>(deg, row_start, chunkSums, N);
    scan_sums<<<1, 128, 0, stream>>>(chunkSums, nChunks);
    scan_add<<<(N + 255) / 256, 256, 0, stream>>>(row_start, chunkSums, N, E);
    fill_k<<<(E + 255) / 256, 256, 0, stream>>>(dst, E, row_start, cursor, csr);

    // one-time edge-data permutation into CSR order
    if (pre) {
        gather_edges<<<((size_t)E * 4 + 255) / 256, 256, 0, stream>>>(
            csr, src, (const float4*)eattr, csr_src, csr_ea, E);
    }

    // 3 transformer layers
    const float* Hin = x;
    for (int l = 0; l < 3; ++l) {
        gemm_qkvs<<<1024, 256, 0, stream>>>(Hin,
            Wq + l * 4096, bq + l * 64, Wk + l * 4096, bk + l * 64,
            Wv + l * 4096, bv + l * 64, Wskip + l * 4096, bskip + l * 64,
            Q, KV, S, N);
        if (pre) {
            attn_pre<<<4096, 256, 0, stream>>>(Q, (const float2*)KV, S,
                row_start, csr_src, (const float*)csr_ea,
                We + l * 1024, be + l * 64, H, N, (l < 2) ? 1 : 0);
        } else {
            attn_k<<<4096, 256, 0, stream>>>(Q, (const float2*)KV, S,
                row_start, csr, src, eattr,
                We + l * 1024, be + l * 64, H, N, (l < 2) ? 1 : 0);
        }
        Hin = H;
    }

    // pool + head
    int poolBlocks = (N + POOL_CHUNK - 1) / POOL_CHUNK;
    pool_k<<<poolBlocks, 64, 0, stream>>>(Hin, batch, pooled, cnt, N);
    mlp_k<<<128, 64, 0, stream>>>(pooled, cnt, lin1_w, lin1_b, lin2_w, lin2_b,
                                  (float*)d_out);
}